// Round 5
// baseline (113.837 us; speedup 1.0000x reference)
//
#include <hip/hip_runtime.h>
#include <hip/hip_bf16.h>

#define B_    4
#define CIN_  64
#define H_    128
#define W_    128
#define COUT_ 64
#define KK_   9
#define OFFC_ 18
#define HW_   (H_*W_)
#define TILE_ 64

typedef short bf8  __attribute__((ext_vector_type(8)));   // 8 bf16 (4 VGPRs)
typedef float f32x4 __attribute__((ext_vector_type(4)));

__device__ inline short f2bf(float f) {
    union { __hip_bfloat16 h; short s; } u; u.h = __float2bfloat16(f); return u.s;
}

// ---------------------------------------------------------------------------
// Prep (single launch): blocks 0..1023 transpose x -> NHWC bf16;
// blocks 1024..1167 repack weights to bf16 MFMA layout.
//   xt[b][y][x][c]   dwbf[k][o][c] (9*64*64)   owbf[k][co<32][c] (pad rows 0)
// ---------------------------------------------------------------------------
__global__ __launch_bounds__(256) void prep_all(
    const float* __restrict__ x,
    const float* __restrict__ ow, const float* __restrict__ dw,
    short* __restrict__ xt, short* __restrict__ dwbf, short* __restrict__ owbf)
{
    const int tid = threadIdx.x;
    const int bid = blockIdx.x;
    if (bid < 1024) {
        const int b  = bid >> 8;
        const int pb = bid & 255;
        const int p  = tid & 63;
        const int g  = tid >> 6;             // channel group 0..3 (16 ch)
        const int pix = pb * 64 + p;
        const float* src = x + ((size_t)b * CIN_ + g * 16) * HW_ + pix;
        short vals[16];
        #pragma unroll
        for (int j = 0; j < 16; ++j) vals[j] = f2bf(src[(size_t)j * HW_]);
        short* dst = xt + ((size_t)b * HW_ + pix) * 64 + g * 16;
        *(bf8*)dst       = *(bf8*)&vals[0];
        *(bf8*)(dst + 8) = *(bf8*)&vals[8];
    } else {
        const int idx = (bid - 1024) * 256 + tid;   // 0..36863
        {   // dwbf: 9*64*64 = 36864
            const int k = idx / (COUT_ * CIN_);
            const int r = idx % (COUT_ * CIN_);
            const int o = r >> 6, c = r & 63;
            dwbf[idx] = f2bf(dw[(o * CIN_ + c) * KK_ + k]);
        }
        if (idx < KK_ * 32 * CIN_) {                // 18432
            const int k = idx / (32 * CIN_);
            const int r = idx % (32 * CIN_);
            const int co = r >> 6, c = r & 63;
            owbf[idx] = f2bf(co < OFFC_ ? ow[(co * CIN_ + c) * KK_ + k] : 0.0f);
        }
    }
}

// ---------------------------------------------------------------------------
// Fused kernel. Block = 256 thr (4 waves) = 64 pixels (half row), grid (256,4).
// Phase A: offset conv via MFMA from an LDS-staged x patch (chunk-XOR swizzle).
// Phase B: barrier-free. Each wave owns 16 pixels; per tap, 4 corner GEMMs
//   with B-fragments loaded straight from NHWC global, then combined with
//   per-pixel masked bilinear weights:  out = sum_corner m_c * (W @ v_c).
// ---------------------------------------------------------------------------
__global__ __launch_bounds__(256, 4) void fused_deform_mfma(
    const short* __restrict__ xt,    // (B,HW,64) bf16 channels-last
    const short* __restrict__ owbf,  // [9][32][64] bf16
    const float* __restrict__ obias, // (18,)
    const short* __restrict__ dwbf,  // [9][64][64] bf16
    const float* __restrict__ dbias, // (64,)
    float* __restrict__ out)         // (B,64,128,128) f32
{
    __shared__ short xtl[3 * 66 * 64];       // [y][q][c], q = col+1 (25.3 KB)
    __shared__ float offs[OFFC_ * TILE_];

    const int tid = threadIdx.x;
    const int b   = blockIdx.y;
    const int pixbase = blockIdx.x * TILE_;
    const int ho    = pixbase >> 7;
    const int wbase = pixbase & (W_ - 1);
    const int lane  = tid & 63;
    const int wv    = tid >> 6;              // wave 0..3
    const int arow  = lane & 15;             // MFMA frag row/col index
    const int kseg  = lane >> 4;             // 0..3

    const short* xbt = xt + (size_t)b * HW_ * 64;

    // ---- stage x patch (3 rows x 66 cols x 64 ch) once, swizzled ----
    for (int base = 0; base < 3 * 66 * 8; base += 256) {
        const int idx = base + tid;
        if (idx < 3 * 66 * 8) {
            const int cc = idx & 7;          // c-chunk
            const int qy = idx >> 3;         // 0..197
            const int y  = qy / 66;
            const int q  = qy - y * 66;
            const int gy = ho + y - 1;
            const int gx = wbase + q - 1;
            bf8 v;
            if (gy >= 0 && gy < H_ && gx >= 0 && gx < W_) {
                v = *(const bf8*)&xbt[(size_t)(gy * W_ + gx) * 64 + cc * 8];
            } else {
                #pragma unroll
                for (int j = 0; j < 8; ++j) v[j] = 0;
            }
            *(bf8*)&xtl[(y * 66 + q) * 64 + ((cc ^ (q & 7)) << 3)] = v;
        }
    }
    __syncthreads();

    // ---- Phase A: offset conv via MFMA ----
    {
        const int m = wv & 1;                // co tile
        const int h = wv >> 1;               // pixel half
        f32x4 acca[2];
        acca[0] = (f32x4)0.f; acca[1] = (f32x4)0.f;
        for (int t = 0; t < KK_; ++t) {
            const int ky = t / 3, kx = t % 3;
            #pragma unroll
            for (int kc = 0; kc < 2; ++kc) {
                const int cbase = kc * 32 + kseg * 8;
                const bf8 afrag = *(const bf8*)&owbf[(t * 32 + m * 16 + arow) * 64 + cbase];
                const int cchunk = cbase >> 3;
                #pragma unroll
                for (int nt = 0; nt < 2; ++nt) {
                    const int pp = h * 32 + nt * 16 + arow;
                    const int q = pp + kx;
                    const bf8 bfrag = *(const bf8*)&xtl[(ky * 66 + q) * 64 + ((cchunk ^ (q & 7)) << 3)];
                    acca[nt] = __builtin_amdgcn_mfma_f32_16x16x32_bf16(afrag, bfrag, acca[nt], 0, 0, 0);
                }
            }
        }
        #pragma unroll
        for (int nt = 0; nt < 2; ++nt) {
            #pragma unroll
            for (int r = 0; r < 4; ++r) {
                const int co = m * 16 + kseg * 4 + r;
                if (co < OFFC_) {
                    const int pp = h * 32 + nt * 16 + arow;
                    offs[co * TILE_ + pp] = acca[nt][r] + obias[co];
                }
            }
        }
    }
    __syncthreads();   // offs ready; no further barriers

    // ---- Phase B: wave-independent corner-GEMM deformable conv ----
    const int pcol = wv * 16 + arow;         // my pixel within the 64-tile
    const int wo   = wbase + pcol;

    f32x4 oacc[4];
    #pragma unroll
    for (int m = 0; m < 4; ++m) oacc[m] = (f32x4)0.f;

    for (int t = 0; t < KK_; ++t) {
        const int ky = t / 3, kx = t % 3;
        const float dy = offs[(2 * t + 0) * TILE_ + pcol];
        const float dx = offs[(2 * t + 1) * TILE_ + pcol];
        const float ys = (float)(ho + ky - 1) + dy;
        const float xs = (float)(wo + kx - 1) + dx;
        const float y0f = floorf(ys), x0f = floorf(xs);
        const float ly = ys - y0f, lx = xs - x0f;
        const int y0 = (int)y0f, x0 = (int)x0f;
        const int y1 = y0 + 1,   x1 = x0 + 1;
        const bool y0v = (y0 >= 0) & (y0 < H_);
        const bool y1v = (y1 >= 0) & (y1 < H_);
        const bool x0v = (x0 >= 0) & (x0 < W_);
        const bool x1v = (x1 >= 0) & (x1 < W_);
        const float mv00 = (y0v & x0v) ? (1.f - ly) * (1.f - lx) : 0.f;
        const float mv01 = (y0v & x1v) ? (1.f - ly) * lx         : 0.f;
        const float mv10 = (y1v & x0v) ? ly * (1.f - lx)         : 0.f;
        const float mv11 = (y1v & x1v) ? ly * lx                 : 0.f;
        const int y0c = min(max(y0, 0), H_ - 1);
        const int y1c = min(max(y1, 0), H_ - 1);
        const int x0c = min(max(x0, 0), W_ - 1);
        const int x1c = min(max(x1, 0), W_ - 1);
        const short* c00 = xbt + (size_t)(y0c * W_ + x0c) * 64 + kseg * 8;
        const short* c01 = xbt + (size_t)(y0c * W_ + x1c) * 64 + kseg * 8;
        const short* c10 = xbt + (size_t)(y1c * W_ + x0c) * 64 + kseg * 8;
        const short* c11 = xbt + (size_t)(y1c * W_ + x1c) * 64 + kseg * 8;

        // corner B-fragments, straight from global (16 B/lane each)
        const bf8 b00a = *(const bf8*)(c00);      const bf8 b00b = *(const bf8*)(c00 + 32);
        const bf8 b01a = *(const bf8*)(c01);      const bf8 b01b = *(const bf8*)(c01 + 32);
        const bf8 b10a = *(const bf8*)(c10);      const bf8 b10b = *(const bf8*)(c10 + 32);
        const bf8 b11a = *(const bf8*)(c11);      const bf8 b11b = *(const bf8*)(c11 + 32);

        const short* apb = dwbf + (size_t)(t * 64 + arow) * 64 + kseg * 8;
        #pragma unroll
        for (int m = 0; m < 4; ++m) {
            const short* ap = apb + m * 16 * 64;
            const bf8 a0 = *(const bf8*)(ap);
            const bf8 a1 = *(const bf8*)(ap + 32);
            f32x4 g00 = (f32x4)0.f, g01 = (f32x4)0.f, g10 = (f32x4)0.f, g11 = (f32x4)0.f;
            g00 = __builtin_amdgcn_mfma_f32_16x16x32_bf16(a0, b00a, g00, 0, 0, 0);
            g00 = __builtin_amdgcn_mfma_f32_16x16x32_bf16(a1, b00b, g00, 0, 0, 0);
            g01 = __builtin_amdgcn_mfma_f32_16x16x32_bf16(a0, b01a, g01, 0, 0, 0);
            g01 = __builtin_amdgcn_mfma_f32_16x16x32_bf16(a1, b01b, g01, 0, 0, 0);
            g10 = __builtin_amdgcn_mfma_f32_16x16x32_bf16(a0, b10a, g10, 0, 0, 0);
            g10 = __builtin_amdgcn_mfma_f32_16x16x32_bf16(a1, b10b, g10, 0, 0, 0);
            g11 = __builtin_amdgcn_mfma_f32_16x16x32_bf16(a0, b11a, g11, 0, 0, 0);
            g11 = __builtin_amdgcn_mfma_f32_16x16x32_bf16(a1, b11b, g11, 0, 0, 0);
            oacc[m] += mv00 * g00 + mv01 * g01 + mv10 * g10 + mv11 * g11;
        }
    }

    // ---- epilogue: o = m*16 + kseg*4 + r, pixel = pixbase + pcol ----
    float* ob = out + (size_t)b * COUT_ * HW_ + pixbase;
    #pragma unroll
    for (int m = 0; m < 4; ++m) {
        #pragma unroll
        for (int r = 0; r < 4; ++r) {
            const int o = m * 16 + kseg * 4 + r;
            ob[(size_t)o * HW_ + pcol] = oacc[m][r] + dbias[o];
        }
    }
}

extern "C" void kernel_launch(void* const* d_in, const int* in_sizes, int n_in,
                              void* d_out, int out_size, void* d_ws, size_t ws_size,
                              hipStream_t stream) {
    const float* x        = (const float*)d_in[0];
    const float* offset_w = (const float*)d_in[1];
    const float* offset_b = (const float*)d_in[2];
    const float* deform_w = (const float*)d_in[3];
    const float* deform_b = (const float*)d_in[4];
    float* out = (float*)d_out;

    short* dwbf = (short*)d_ws;                        // 73728 B
    short* owbf = (short*)((char*)d_ws + 73728);       // 36864 B
    short* xt   = (short*)((char*)d_ws + 110592);      // 8 MB NHWC bf16

    prep_all<<<1024 + 144, 256, 0, stream>>>(x, offset_w, deform_w, xt, dwbf, owbf);

    dim3 grid(HW_ / TILE_, B_);
    fused_deform_mfma<<<grid, 256, 0, stream>>>(xt, owbf, offset_b, dwbf, deform_b, out);
}